// Round 12
// baseline (240.364 us; speedup 1.0000x reference)
//
#include <hip/hip_runtime.h>
#include <hip/hip_bf16.h>
#include <stdint.h>

typedef unsigned short ushort_t;
typedef __attribute__((ext_vector_type(8))) short short8;
typedef __attribute__((ext_vector_type(4))) float floatx4;

// ---------- helpers ----------
__device__ __forceinline__ ushort_t f2bf(float f) {
    union { float f; unsigned u; } v; v.f = f;
    unsigned r = v.u + 0x7fffu + ((v.u >> 16) & 1u);   // RTNE
    return (ushort_t)(r >> 16);
}

__device__ __forceinline__ void async16(ushort_t* lds, const ushort_t* g) {
    __builtin_amdgcn_global_load_lds(
        (const __attribute__((address_space(1))) unsigned int*)g,
        (__attribute__((address_space(3))) unsigned int*)lds, 16, 0, 0);
}

// Counted waits + compiler-fenced raw barrier (T4, r7-verified).
// r12: SINGLE barrier per K-step via triple buffer + issue-after-compute.
// Safety: at step s, each wave waits vmcnt(4) for its own step-s loads,
// then barriers (=> all waves' step-s staging complete before any read);
// the step-(s+2) issue targets buf (s-1)%3 whose readers finished before
// each wave's barrier_s (in-wave program order + lgkmcnt-before-MFMA), and
// the issue is after barrier_s. Halves barrier count vs r6-r11.
#define WAIT_VMCNT(n) asm volatile("s_waitcnt vmcnt(" #n ")" ::: "memory")
__device__ __forceinline__ void barrier_nodrain() {
    asm volatile("" ::: "memory");
    __builtin_amdgcn_s_barrier();
    asm volatile("" ::: "memory");
}

// ---------- fused prep: cvt x -> bf16 (grid-stride), A2b, Bg1 ----------
// Semantics (round-1 lesson): reference reshapes (i0,i1,o0,o1) flat to
// (4096,1024) WITHOUT transpose: out[m][4a+b] uses ii=a, oo=b*1024+c.
// => out[m][4a+b] = sum_k A2[a][k] * (sum_c x[m][c] B2[b*1024+c][k])
// blocks [0,2048): cvt; [2048,3072): A2b; [3072,7168): Bg1
__global__ __launch_bounds__(256) void prep_all(const float* __restrict__ x,
                                                const float* __restrict__ c0,
                                                const float* __restrict__ c1,
                                                const float* __restrict__ c2,
                                                const float* __restrict__ c3,
                                                ushort_t* __restrict__ Xb,
                                                ushort_t* __restrict__ A2b,
                                                ushort_t* __restrict__ Bg1) {
    const int b = blockIdx.x, t = threadIdx.x;
    if (b < 2048) {
        int i = b * 256 + t;                       // float4 index; 2M total
#pragma unroll
        for (int it = 0; it < 4; it++) {
            int idx = i + it * (2048 * 256);
            float4 v = ((const float4*)x)[idx];
            ushort4 r;
            r.x = f2bf(v.x); r.y = f2bf(v.y); r.z = f2bf(v.z); r.w = f2bf(v.w);
            ((ushort4*)Xb)[idx] = r;
        }
    } else if (b < 3072) {
        // A2b[ii][k] = sum_r1 c0[r0,i0,r1]*c1[r1,i1,r2], k = r0*16+r2
        int id = (b - 2048) * 256 + t;             // [0, 1024*256)
        int k = id & 255, ii = id >> 8;
        int r0 = k >> 4, r2 = k & 15;
        int i0 = ii >> 5, i1 = ii & 31;
        const float* p0 = c0 + (r0 * 32 + i0) * 16;   // stride 1 over r1
        const float* p1 = c1 + i1 * 16 + r2;          // stride 512 over r1
        float s = 0.f;
#pragma unroll
        for (int r1 = 0; r1 < 16; r1++) s += p0[r1] * p1[r1 * 512];
        A2b[id] = f2bf(s);                         // A2b[ii*256 + k]
    } else {
        // Bg1[n][c] = B2[(n>>8)*1024 + c][n&255], n = b*256+k
        // B2[oo][k] = sum_r3 c2[r2,o0,r3]*c3[r3,o1,r0], k=r0*16+r2
        int id = (b - 3072) * 256 + t;             // [0, 1024*1024)
        int c = id & 1023, n = id >> 10;
        int bq = n >> 8, k = n & 255;
        int r0 = k >> 4, r2 = k & 15;
        int o0 = bq * 16 + (c >> 6), o1 = c & 63;
        const float* p2 = c2 + (r2 * 64 + o0) * 16;   // stride 1 over r3
        const float* p3 = c3 + o1 * 16 + r0;          // stride 1024 over r3
        float s = 0.f;
#pragma unroll
        for (int r3 = 0; r3 < 16; r3++) s += p2[r3] * p3[r3 * 1024];
        Bg1[id] = f2bf(s);                         // Bg1[n*1024 + c], c-coalesced
    }
}

// ---------- GEMM1 (triple-buf, 1 barrier/step): U = Xb @ Bg1^T ----------
// M=8192, N=1024, K=1024. 128x128 tile (r7-verified fragments/epilogue),
// 512 blocks, XCD chunk-swizzle. 4 loads/step, steady wait vmcnt(4).
// LDS 48 KB -> 3 blocks/CU (only 2 needed: 512 blocks all-resident).
__global__ __launch_bounds__(256) void gemm1_u(const ushort_t* __restrict__ Xb,
                                               const ushort_t* __restrict__ Bg1,
                                               ushort_t* __restrict__ U) {
    __shared__ ushort_t As[3][128 * 32];   // 24 KB
    __shared__ ushort_t Bs[3][128 * 32];   // 24 KB
    const int t = threadIdx.x;
    const unsigned orig = blockIdx.x;                      // 512
    const unsigned wg = (orig & 7) * 64 + (orig >> 3);     // bijective, 512%8==0
    const int row0 = (int)(wg >> 3) * 128;  // m-tile
    const int col0 = (int)(wg & 7) * 128;   // n-tile
    const int w = t >> 6, l = t & 63;
    const int wm = w >> 1, wn = w & 1;
    const int quad = l >> 4, ln = l & 15;

    floatx4 acc[4][4] = {};

    const ushort_t* aSrc = Xb  + (size_t)(row0 + (t >> 2)) * 1024 + (t & 3) * 8;
    const ushort_t* bSrc = Bg1 + (size_t)(col0 + (t >> 2)) * 1024 + (t & 3) * 8;

    // prologue: stage steps 0,1 into bufs 0,1 (8 loads in flight)
    async16(&As[0][t * 8],        aSrc);
    async16(&As[0][2048 + t * 8], aSrc + 64 * 1024);
    async16(&Bs[0][t * 8],        bSrc);
    async16(&Bs[0][2048 + t * 8], bSrc + 64 * 1024);
    async16(&As[1][t * 8],        aSrc + 32);
    async16(&As[1][2048 + t * 8], aSrc + 64 * 1024 + 32);
    async16(&Bs[1][t * 8],        bSrc + 32);
    async16(&Bs[1][2048 + t * 8], bSrc + 64 * 1024 + 32);

    int cb = 0, wb = 2;
#pragma unroll 3
    for (int s = 0; s < 32; ++s) {
        if (s < 31) { WAIT_VMCNT(4); }   // own step-s loads (oldest 4) done
        else        { WAIT_VMCNT(0); }
        barrier_nodrain();               // => ALL waves' step-s staging done

        short8 a[4], b[4];
#pragma unroll
        for (int ti = 0; ti < 4; ti++)
            a[ti] = *(const short8*)&As[cb][(wm * 64 + ti * 16 + ln) * 32 + quad * 8];
#pragma unroll
        for (int tj = 0; tj < 4; tj++)
            b[tj] = *(const short8*)&Bs[cb][(wn * 64 + tj * 16 + ln) * 32 + quad * 8];
#pragma unroll
        for (int ti = 0; ti < 4; ti++)
#pragma unroll
            for (int tj = 0; tj < 4; tj++)
                acc[ti][tj] = __builtin_amdgcn_mfma_f32_16x16x32_bf16(
                    a[ti], b[tj], acc[ti][tj], 0, 0, 0);

        if (s < 30) {                    // issue step s+2 into buf (s+2)%3
            const int kkw = (s + 2) * 32;
            async16(&As[wb][t * 8],        aSrc + kkw);
            async16(&As[wb][2048 + t * 8], aSrc + 64 * 1024 + kkw);
            async16(&Bs[wb][t * 8],        bSrc + kkw);
            async16(&Bs[wb][2048 + t * 8], bSrc + 64 * 1024 + kkw);
        }
        cb = (cb == 2) ? 0 : cb + 1;
        wb = (wb == 2) ? 0 : wb + 1;
    }

    // D layout col=lane&15, row=quad*4+reg  [m89]; store bf16 U
#pragma unroll
    for (int tj = 0; tj < 4; tj++) {
        const int n = col0 + wn * 64 + tj * 16 + ln;
#pragma unroll
        for (int ti = 0; ti < 4; ti++) {
            const int m = row0 + wm * 64 + ti * 16 + quad * 4;
#pragma unroll
            for (int r = 0; r < 4; r++)
                U[(size_t)(m + r) * 1024 + n] = f2bf(acc[ti][tj][r]);
        }
    }
}

// ---------- GEMM2 (triple-buf, 1 barrier/step) ----------
// out[m][4a+b] = sum_k U[m][b*256+k]*A2b[a][k] + bias
// M=8192, j=4096 (a=1024, b=4). Block: 64m x (64a x 4b). K=256, 8 steps.
// 2048 blocks; A2 tile in REGS (r4/r7-verified layout, loaded FIRST =
// oldest in vmcnt order -> counted waits conservative-correct).
// Us 3 bufs x 16 KB = 48 KB -> 3 blocks/CU (same as r7's VGPR limit).
// Fully unrolled: buffer indices and a2f[.][s] stay compile-time (rule #20).
__global__ __launch_bounds__(256) void gemm2_tr(const ushort_t* __restrict__ U,
                                                const ushort_t* __restrict__ A2b,
                                                const float* __restrict__ bias,
                                                float* __restrict__ out) {
    __shared__ ushort_t Us[3][4][64 * 32];   // 48 KB
    const int t = threadIdx.x;
    const unsigned orig = blockIdx.x;                       // 2048
    const unsigned wg = (orig & 7) * 256 + (orig >> 3);     // bijective, 2048%8==0
    const int jt = (int)(wg & 15), mt = (int)(wg >> 4);     // 16 a-tiles, 128 m-tiles
    const int row0 = mt * 64;
    const int a0 = jt * 64;
    const int w = t >> 6, l = t & 63;
    const int wm = w >> 1, wn = w & 1;
    const int quad = l >> 4, ln = l & 15;

    // A2 B-operand fragments in regs: rows = a (by ln), k by quad;
    // a2f[tj][s] covers k = s*32.
    short8 a2f[2][8];
#pragma unroll
    for (int tj = 0; tj < 2; tj++) {
        const ushort_t* ap = A2b + (size_t)(a0 + wn * 32 + tj * 16 + ln) * 256 + quad * 8;
#pragma unroll
        for (int s = 0; s < 8; s++)
            a2f[tj][s] = *(const short8*)&ap[s * 32];
    }

    floatx4 acc[4][2][2] = {};   // [b][ti][tj]

    const ushort_t* uSrc = U + (size_t)(row0 + (t >> 2)) * 1024 + (t & 3) * 8;

    // prologue: stage steps 0,1 into bufs 0,1 (8 loads)
#pragma unroll
    for (int b = 0; b < 4; b++)
        async16(&Us[0][b][t * 8], uSrc + b * 256);
#pragma unroll
    for (int b = 0; b < 4; b++)
        async16(&Us[1][b][t * 8], uSrc + b * 256 + 32);

#pragma unroll
    for (int s = 0; s < 8; s++) {
        if (s < 7) { WAIT_VMCNT(4); }    // step-s loads (oldest beyond a2f) done
        else       { WAIT_VMCNT(0); }
        barrier_nodrain();

        const int cb = s % 3;            // static after full unroll
#pragma unroll
        for (int b = 0; b < 4; b++) {
            short8 au[2];
#pragma unroll
            for (int ti = 0; ti < 2; ti++)
                au[ti] = *(const short8*)&Us[cb][b][(wm * 32 + ti * 16 + ln) * 32 + quad * 8];
#pragma unroll
            for (int ti = 0; ti < 2; ti++)
#pragma unroll
                for (int tj = 0; tj < 2; tj++)
                    acc[b][ti][tj] = __builtin_amdgcn_mfma_f32_16x16x32_bf16(
                        au[ti], a2f[tj][s], acc[b][ti][tj], 0, 0, 0);
        }
        if (s < 6) {                     // issue step s+2 into buf (s+2)%3
            const int wb = (s + 2) % 3;  // static after full unroll
#pragma unroll
            for (int b = 0; b < 4; b++)
                async16(&Us[wb][b][t * 8], uSrc + b * 256 + (s + 2) * 32);
        }
    }

    // epilogue: lane holds D[m=quad*4+r][a=ln] per (b,ti,tj); pack b into float4
#pragma unroll
    for (int tj = 0; tj < 2; tj++) {
        const int a = a0 + wn * 32 + tj * 16 + ln;
        const float4 bv = ((const float4*)bias)[a];
#pragma unroll
        for (int ti = 0; ti < 2; ti++) {
            const int m = row0 + wm * 32 + ti * 16 + quad * 4;
#pragma unroll
            for (int r = 0; r < 4; r++) {
                float4 o;
                o.x = acc[0][ti][tj][r] + bv.x;
                o.y = acc[1][ti][tj][r] + bv.y;
                o.z = acc[2][ti][tj][r] + bv.z;
                o.w = acc[3][ti][tj][r] + bv.w;
                *(float4*)&out[(size_t)(m + r) * 4096 + (size_t)a * 4] = o;
            }
        }
    }
}

extern "C" void kernel_launch(void* const* d_in, const int* in_sizes, int n_in,
                              void* d_out, int out_size, void* d_ws, size_t ws_size,
                              hipStream_t stream) {
    const float* x    = (const float*)d_in[0];   // 8192*1024
    const float* c0   = (const float*)d_in[1];   // 16*32*16
    const float* c1   = (const float*)d_in[2];   // 16*32*16
    const float* c2   = (const float*)d_in[3];   // 16*64*16
    const float* c3   = (const float*)d_in[4];   // 16*64*16
    const float* bias = (const float*)d_in[5];   // 4096
    float* out = (float*)d_out;                  // 8192*4096 f32 (128 MB)

    // Workspace <= 19 MB (r3-r11 proven). Xb scratch lives in the FIRST
    // 16 MB of `out` — dead before gemm2_tr's first store; kernels serialize
    // on the stream.
    char* ws = (char*)d_ws;
    ushort_t* Xb  = (ushort_t*)out;                       // 16 MB bf16 x (in d_out)
    ushort_t* U   = (ushort_t*)ws;                        // 16 MB bf16 U[m][b*256+k]
    ushort_t* A2b = (ushort_t*)(ws + (16u << 20));        // 0.5 MB bf16 A2b[ii*256+k]
    ushort_t* Bg1 = (ushort_t*)(ws + (17u << 20));        //  2 MB bf16 Bg1[n*1024+c]

    hipLaunchKernelGGL(prep_all, dim3(7168), dim3(256), 0, stream,
                       x, c0, c1, c2, c3, Xb, A2b, Bg1);
    hipLaunchKernelGGL(gemm1_u, dim3(512), dim3(256), 0, stream, Xb, Bg1, U);
    hipLaunchKernelGGL(gemm2_tr, dim3(2048), dim3(256), 0, stream, U, A2b, bias, out);
}

// Round 13
// 235.848 us; speedup vs baseline: 1.0191x; 1.0191x over previous
//
#include <hip/hip_runtime.h>
#include <hip/hip_bf16.h>
#include <stdint.h>

typedef unsigned short ushort_t;
typedef __attribute__((ext_vector_type(8))) short short8;
typedef __attribute__((ext_vector_type(4))) float floatx4;

// ---------- helpers ----------
__device__ __forceinline__ ushort_t f2bf(float f) {
    union { float f; unsigned u; } v; v.f = f;
    unsigned r = v.u + 0x7fffu + ((v.u >> 16) & 1u);   // RTNE
    return (ushort_t)(r >> 16);
}

__device__ __forceinline__ void async16(ushort_t* lds, const ushort_t* g) {
    __builtin_amdgcn_global_load_lds(
        (const __attribute__((address_space(1))) unsigned int*)g,
        (__attribute__((address_space(3))) unsigned int*)lds, 16, 0, 0);
}

// Counted waits + compiler-fenced raw barrier (T4). This is the r7 kernel,
// byte-for-byte — the session's best measurement (237.0 us). r8-r12 tested
// depth-3 (245.6), 2x-MFMA-per-barrier (245.9), prep grid-stride (238.9),
// single-barrier tri-buf (240.4): all tied or regressed. The K-loop schedule
// is no longer the binding constraint; restoring the empirical best.
#define WAIT_VMCNT(n) asm volatile("s_waitcnt vmcnt(" #n ")" ::: "memory")
__device__ __forceinline__ void barrier_nodrain() {
    asm volatile("" ::: "memory");
    __builtin_amdgcn_s_barrier();
    asm volatile("" ::: "memory");
}

// ---------- fused prep: cvt x -> bf16, A2b[ii][k], Bg1[n][c] (bf16) ----------
// Semantics (round-1 lesson): reference reshapes (i0,i1,o0,o1) flat to
// (4096,1024) WITHOUT transpose: out[m][4a+b] uses ii=a, oo=b*1024+c.
// => out[m][4a+b] = sum_k A2[a][k] * (sum_c x[m][c] B2[b*1024+c][k])
// blocks [0,8192): cvt; [8192,9216): A2b; [9216,13312): Bg1
__global__ __launch_bounds__(256) void prep_all(const float* __restrict__ x,
                                                const float* __restrict__ c0,
                                                const float* __restrict__ c1,
                                                const float* __restrict__ c2,
                                                const float* __restrict__ c3,
                                                ushort_t* __restrict__ Xb,
                                                ushort_t* __restrict__ A2b,
                                                ushort_t* __restrict__ Bg1) {
    const int b = blockIdx.x, t = threadIdx.x;
    if (b < 8192) {
        int i = b * 256 + t;                       // float4 index, n4 = 2M
        float4 v = ((const float4*)x)[i];
        ushort4 r;
        r.x = f2bf(v.x); r.y = f2bf(v.y); r.z = f2bf(v.z); r.w = f2bf(v.w);
        ((ushort4*)Xb)[i] = r;
    } else if (b < 9216) {
        // A2b[ii][k] = sum_r1 c0[r0,i0,r1]*c1[r1,i1,r2], k = r0*16+r2
        int id = (b - 8192) * 256 + t;             // [0, 1024*256)
        int k = id & 255, ii = id >> 8;
        int r0 = k >> 4, r2 = k & 15;
        int i0 = ii >> 5, i1 = ii & 31;
        const float* p0 = c0 + (r0 * 32 + i0) * 16;   // stride 1 over r1
        const float* p1 = c1 + i1 * 16 + r2;          // stride 512 over r1
        float s = 0.f;
#pragma unroll
        for (int r1 = 0; r1 < 16; r1++) s += p0[r1] * p1[r1 * 512];
        A2b[id] = f2bf(s);                         // A2b[ii*256 + k]
    } else {
        // Bg1[n][c] = B2[(n>>8)*1024 + c][n&255], n = b*256+k
        // B2[oo][k] = sum_r3 c2[r2,o0,r3]*c3[r3,o1,r0], k=r0*16+r2
        int id = (b - 9216) * 256 + t;             // [0, 1024*1024)
        int c = id & 1023, n = id >> 10;
        int bq = n >> 8, k = n & 255;
        int r0 = k >> 4, r2 = k & 15;
        int o0 = bq * 16 + (c >> 6), o1 = c & 63;
        const float* p2 = c2 + (r2 * 64 + o0) * 16;   // stride 1 over r3
        const float* p3 = c3 + o1 * 16 + r0;          // stride 1024 over r3
        float s = 0.f;
#pragma unroll
        for (int r3 = 0; r3 < 16; r3++) s += p2[r3] * p3[r3 * 1024];
        Bg1[id] = f2bf(s);                         // Bg1[n*1024 + c], c-coalesced
    }
}

// ---------- GEMM1 (2-phase dbuf + counted vmcnt): U = Xb @ Bg1^T ----------
// M=8192, N=1024, K=1024. 128x128 tile, 512 blocks, XCD chunk-swizzle.
// Per step: issue 4 prefetch -> vmcnt(4) -> barrier -> compute -> barrier.
// The just-issued 4 loads stay in flight across both barriers (T4).
__global__ __launch_bounds__(256) void gemm1_u(const ushort_t* __restrict__ Xb,
                                               const ushort_t* __restrict__ Bg1,
                                               ushort_t* __restrict__ U) {
    __shared__ ushort_t As[2][128 * 32];
    __shared__ ushort_t Bs[2][128 * 32];
    const int t = threadIdx.x;
    const unsigned orig = blockIdx.x;                      // 512
    const unsigned wg = (orig & 7) * 64 + (orig >> 3);     // bijective, 512%8==0
    const int row0 = (int)(wg >> 3) * 128;  // m-tile
    const int col0 = (int)(wg & 7) * 128;   // n-tile
    const int w = t >> 6, l = t & 63;
    const int wm = w >> 1, wn = w & 1;
    const int quad = l >> 4, ln = l & 15;

    floatx4 acc[4][4] = {};

    const ushort_t* aSrc = Xb  + (size_t)(row0 + (t >> 2)) * 1024 + (t & 3) * 8;
    const ushort_t* bSrc = Bg1 + (size_t)(col0 + (t >> 2)) * 1024 + (t & 3) * 8;

    // prologue: stage tile 0 into buf 0 (4 loads in flight)
    async16(&As[0][t * 8],        aSrc);
    async16(&As[0][2048 + t * 8], aSrc + 64 * 1024);
    async16(&Bs[0][t * 8],        bSrc);
    async16(&Bs[0][2048 + t * 8], bSrc + 64 * 1024);

    int cur = 0;
#pragma unroll 2
    for (int kk = 32; kk < 1024; kk += 32, cur ^= 1) {
        // issue next-tile stage FIRST (stays in flight across both barriers)
        async16(&As[cur ^ 1][t * 8],        aSrc + kk);
        async16(&As[cur ^ 1][2048 + t * 8], aSrc + 64 * 1024 + kk);
        async16(&Bs[cur ^ 1][t * 8],        bSrc + kk);
        async16(&Bs[cur ^ 1][2048 + t * 8], bSrc + 64 * 1024 + kk);

        WAIT_VMCNT(4);          // previous step's 4 loads (oldest) complete
        barrier_nodrain();      // all waves' cur-buf writes visible

        short8 a[4], b[4];
#pragma unroll
        for (int ti = 0; ti < 4; ti++)
            a[ti] = *(const short8*)&As[cur][(wm * 64 + ti * 16 + ln) * 32 + quad * 8];
#pragma unroll
        for (int tj = 0; tj < 4; tj++)
            b[tj] = *(const short8*)&Bs[cur][(wn * 64 + tj * 16 + ln) * 32 + quad * 8];
#pragma unroll
        for (int ti = 0; ti < 4; ti++)
#pragma unroll
            for (int tj = 0; tj < 4; tj++)
                acc[ti][tj] = __builtin_amdgcn_mfma_f32_16x16x32_bf16(
                    a[ti], b[tj], acc[ti][tj], 0, 0, 0);

        barrier_nodrain();      // fence cur-buf reuse by next step's prefetch
    }
    // epilogue: last tile (cur) — drain remaining loads, then compute
    WAIT_VMCNT(0);
    barrier_nodrain();
    {
        short8 a[4], b[4];
#pragma unroll
        for (int ti = 0; ti < 4; ti++)
            a[ti] = *(const short8*)&As[cur][(wm * 64 + ti * 16 + ln) * 32 + quad * 8];
#pragma unroll
        for (int tj = 0; tj < 4; tj++)
            b[tj] = *(const short8*)&Bs[cur][(wn * 64 + tj * 16 + ln) * 32 + quad * 8];
#pragma unroll
        for (int ti = 0; ti < 4; ti++)
#pragma unroll
            for (int tj = 0; tj < 4; tj++)
                acc[ti][tj] = __builtin_amdgcn_mfma_f32_16x16x32_bf16(
                    a[ti], b[tj], acc[ti][tj], 0, 0, 0);
    }

    // D layout col=lane&15, row=quad*4+reg  [m89]; store bf16 U
#pragma unroll
    for (int tj = 0; tj < 4; tj++) {
        const int n = col0 + wn * 64 + tj * 16 + ln;
#pragma unroll
        for (int ti = 0; ti < 4; ti++) {
            const int m = row0 + wm * 64 + ti * 16 + quad * 4;
#pragma unroll
            for (int r = 0; r < 4; r++)
                U[(size_t)(m + r) * 1024 + n] = f2bf(acc[ti][tj][r]);
        }
    }
}

// ---------- GEMM2 (2-phase dbuf + counted vmcnt) ----------
// out[m][4a+b] = sum_k U[m][b*256+k]*A2b[a][k] + bias
// M=8192, j=4096 (a=1024, b=4). Block: 64m x (64a x 4b). K=256, 8 steps.
// 2048 blocks; A2 tile in REGS (r4-verified layout); Us dbuf 32 KB.
__global__ __launch_bounds__(256) void gemm2_tr(const ushort_t* __restrict__ U,
                                                const ushort_t* __restrict__ A2b,
                                                const float* __restrict__ bias,
                                                float* __restrict__ out) {
    __shared__ ushort_t Us[2][4][64 * 32];
    const int t = threadIdx.x;
    const unsigned orig = blockIdx.x;                       // 2048
    const unsigned wg = (orig & 7) * 256 + (orig >> 3);     // bijective, 2048%8==0
    const int jt = (int)(wg & 15), mt = (int)(wg >> 4);     // 16 a-tiles, 128 m-tiles
    const int row0 = mt * 64;
    const int a0 = jt * 64;
    const int w = t >> 6, l = t & 63;
    const int wm = w >> 1, wn = w & 1;
    const int quad = l >> 4, ln = l & 15;

    // A2 B-operand fragments in regs (r4-verified per-lane layout):
    // rows = a (by ln), k by quad; a2f[tj][s] covers k = s*32. Loaded FIRST
    // = oldest in vmcnt order, so counted waits stay conservative-correct.
    short8 a2f[2][8];
#pragma unroll
    for (int tj = 0; tj < 2; tj++) {
        const ushort_t* ap = A2b + (size_t)(a0 + wn * 32 + tj * 16 + ln) * 256 + quad * 8;
#pragma unroll
        for (int s = 0; s < 8; s++)
            a2f[tj][s] = *(const short8*)&ap[s * 32];
    }

    floatx4 acc[4][2][2] = {};   // [b][ti][tj]

    const ushort_t* uSrc = U + (size_t)(row0 + (t >> 2)) * 1024 + (t & 3) * 8;

    // prologue: stage k-step 0 into buf 0
#pragma unroll
    for (int b = 0; b < 4; b++)
        async16(&Us[0][b][t * 8], uSrc + b * 256);

    int cur = 0;
#pragma unroll
    for (int kk8 = 1; kk8 < 8; kk8++, cur ^= 1) {
        // prefetch next k-step (stays in flight across both barriers)
#pragma unroll
        for (int b = 0; b < 4; b++)
            async16(&Us[cur ^ 1][b][t * 8], uSrc + b * 256 + kk8 * 32);

        WAIT_VMCNT(4);          // previous step's 4 loads complete
        barrier_nodrain();

        // compute step kk8-1 from Us[cur]
#pragma unroll
        for (int b = 0; b < 4; b++) {
            short8 au[2];
#pragma unroll
            for (int ti = 0; ti < 2; ti++)
                au[ti] = *(const short8*)&Us[cur][b][(wm * 32 + ti * 16 + ln) * 32 + quad * 8];
#pragma unroll
            for (int ti = 0; ti < 2; ti++)
#pragma unroll
                for (int tj = 0; tj < 2; tj++)
                    acc[b][ti][tj] = __builtin_amdgcn_mfma_f32_16x16x32_bf16(
                        au[ti], a2f[tj][kk8 - 1], acc[b][ti][tj], 0, 0, 0);
        }
        barrier_nodrain();
    }
    // epilogue: compute step 7 from Us[cur]
    WAIT_VMCNT(0);
    barrier_nodrain();
#pragma unroll
    for (int b = 0; b < 4; b++) {
        short8 au[2];
#pragma unroll
        for (int ti = 0; ti < 2; ti++)
            au[ti] = *(const short8*)&Us[cur][b][(wm * 32 + ti * 16 + ln) * 32 + quad * 8];
#pragma unroll
        for (int ti = 0; ti < 2; ti++)
#pragma unroll
            for (int tj = 0; tj < 2; tj++)
                acc[b][ti][tj] = __builtin_amdgcn_mfma_f32_16x16x32_bf16(
                    au[ti], a2f[tj][7], acc[b][ti][tj], 0, 0, 0);
    }

    // epilogue: lane holds D[m=quad*4+r][a=ln] per (b,ti,tj); pack b into float4
#pragma unroll
    for (int tj = 0; tj < 2; tj++) {
        const int a = a0 + wn * 32 + tj * 16 + ln;
        const float4 bv = ((const float4*)bias)[a];
#pragma unroll
        for (int ti = 0; ti < 2; ti++) {
            const int m = row0 + wm * 32 + ti * 16 + quad * 4;
#pragma unroll
            for (int r = 0; r < 4; r++) {
                float4 o;
                o.x = acc[0][ti][tj][r] + bv.x;
                o.y = acc[1][ti][tj][r] + bv.y;
                o.z = acc[2][ti][tj][r] + bv.z;
                o.w = acc[3][ti][tj][r] + bv.w;
                *(float4*)&out[(size_t)(m + r) * 4096 + (size_t)a * 4] = o;
            }
        }
    }
}

extern "C" void kernel_launch(void* const* d_in, const int* in_sizes, int n_in,
                              void* d_out, int out_size, void* d_ws, size_t ws_size,
                              hipStream_t stream) {
    const float* x    = (const float*)d_in[0];   // 8192*1024
    const float* c0   = (const float*)d_in[1];   // 16*32*16
    const float* c1   = (const float*)d_in[2];   // 16*32*16
    const float* c2   = (const float*)d_in[3];   // 16*64*16
    const float* c3   = (const float*)d_in[4];   // 16*64*16
    const float* bias = (const float*)d_in[5];   // 4096
    float* out = (float*)d_out;                  // 8192*4096 f32 (128 MB)

    // Workspace <= 19 MB (r3-r12 proven). Xb scratch lives in the FIRST
    // 16 MB of `out` — dead before gemm2_tr's first store; kernels serialize
    // on the stream.
    char* ws = (char*)d_ws;
    ushort_t* Xb  = (ushort_t*)out;                       // 16 MB bf16 x (in d_out)
    ushort_t* U   = (ushort_t*)ws;                        // 16 MB bf16 U[m][b*256+k]
    ushort_t* A2b = (ushort_t*)(ws + (16u << 20));        // 0.5 MB bf16 A2b[ii*256+k]
    ushort_t* Bg1 = (ushort_t*)(ws + (17u << 20));        //  2 MB bf16 Bg1[n*1024+c]

    hipLaunchKernelGGL(prep_all, dim3(13312), dim3(256), 0, stream,
                       x, c0, c1, c2, c3, Xb, A2b, Bg1);
    hipLaunchKernelGGL(gemm1_u, dim3(512), dim3(256), 0, stream, Xb, Bg1, U);
    hipLaunchKernelGGL(gemm2_tr, dim3(2048), dim3(256), 0, stream, U, A2b, bias, out);
}